// Round 2
// baseline (253.875 us; speedup 1.0000x reference)
//
#include <hip/hip_runtime.h>
#include <math.h>

// Problem sizes (fixed by the reference)
constexpr int B_ = 4, S_ = 1024, E_ = 128, H_ = 16, DK_ = 8, F_ = 512;
constexpr int R_ = B_ * S_; // 4096 token rows
#define EPSV 1e-5f

// Workspace layout (float offsets). x1 reuses qc's region (qc dead after attn).
constexpr int OFF_WQT  = 0;
constexpr int OFF_WOT  = OFF_WQT + E_ * E_;   // 16384
constexpr int OFF_W2T  = OFF_WOT + E_ * E_;   // 32768
constexpr int OFF_QC   = OFF_W2T + F_ * E_;   // 98304
constexpr int OFF_X1   = OFF_QC;              // reuse (qc consumed by k_attn)
constexpr int OFF_CTX  = OFF_QC  + R_ * E_;   // 622592
constexpr int OFF_QOUT = OFF_CTX + R_ * E_;   // 1146880
// total ws need ≈ 4.7 MB

// ------------------------------------------------- transpose (reads coalesced)
__global__ __launch_bounds__(256) void k_transpose(const float* __restrict__ Wq,
                                                   const float* __restrict__ Wo,
                                                   const float* __restrict__ W2,
                                                   float* __restrict__ ws) {
    int idx = blockIdx.x * 256 + threadIdx.x;
    if (idx < 16384) {
        int e = idx >> 7, k = idx & 127;
        ws[OFF_WQT + k * 128 + e] = Wq[idx];
    } else if (idx < 32768) {
        int j = idx - 16384;
        int e = j >> 7, k = j & 127;
        ws[OFF_WOT + k * 128 + e] = Wo[j];
    } else if (idx < 98304) {
        int j = idx - 32768;
        int e = j >> 9, f = j & 511;           // W2 is [E=128][F=512]
        ws[OFF_W2T + f * 128 + e] = W2[j];
    }
}

// ------------------------------------------------- q projection + cos(+rx)
// 4 rows/block, 1 row x 2 cols per thread. grid 1024.
__global__ __launch_bounds__(256) void k_qproj(const float* __restrict__ x,
                                               const float* __restrict__ bq,
                                               const float* __restrict__ rx,
                                               const float* __restrict__ WqT,
                                               float* __restrict__ qc) {
    __shared__ __attribute__((aligned(16))) float xs[4][128];
    const int tid = threadIdx.x;
    const int row0 = blockIdx.x * 4;
    if (tid < 128) ((float4*)xs)[tid] = ((const float4*)(x + row0 * E_))[tid];
    __syncthreads();
    const int r = tid >> 6, c0 = (tid & 63) * 2;
    const int gr = row0 + r;
    float a0 = 0.f, a1 = 0.f;
#pragma unroll 8
    for (int k = 0; k < 128; ++k) {
        const float2 w = *(const float2*)(WqT + k * 128 + c0);
        const float u = xs[r][k];
        a0 = fmaf(u, w.x, a0);
        a1 = fmaf(u, w.y, a1);
    }
    const float2 bb = *(const float2*)(bq + c0);
    const float2 rr = *(const float2*)(rx + c0);
    const float o0 = cosf(a0 + bb.x + rr.x);
    const float o1 = cosf(a1 + bb.y + rr.y);
    const int b = gr >> 10, s = gr & 1023;
    const int h = c0 >> 3, d0 = c0 & 7;
    *(float2*)(qc + (((b * H_ + h) * S_ + s) * DK_ + d0)) = make_float2(o0, o1);
}

// ---------------------------------------------------------------- attention
// Bounded scores -> softmax without max subtraction. 2 lanes per query (each
// owns 4 of 8 dims); full dot via DPP quad-swap. K read straight from global
// (uniform per half-wave -> one cache line per key, L1-resident; no LDS).
// grid = 64 (b,h) * 8 q-tiles of 128; block = 256 threads.
__global__ __launch_bounds__(256) void k_attn(const float* __restrict__ qc,
                                              float* __restrict__ ctx) {
    const int tid = threadIdx.x;
    const int bh = blockIdx.x >> 3;
    const int qt = blockIdx.x & 7;
    const float* kbase = qc + bh * (S_ * DK_);
    const int ql = tid >> 1, half = tid & 1;
    const int s0 = qt * 128 + ql;
    const float4 qh = *(const float4*)(kbase + s0 * 8 + half * 4);
    float ax = 0.f, ay = 0.f, az = 0.f, aw = 0.f, lsum = 0.f;
#pragma unroll 8
    for (int t = 0; t < S_; ++t) {
        const float4 kh = *(const float4*)(kbase + t * 8 + half * 4);
        float d = qh.x * kh.x;
        d = fmaf(qh.y, kh.y, d);
        d = fmaf(qh.z, kh.z, d);
        d = fmaf(qh.w, kh.w, d);
        // partner lane's partial dot: quad_perm [1,0,3,2] = 0xB1
        const float dpart = __int_as_float(
            __builtin_amdgcn_mov_dpp(__float_as_int(d), 0xB1, 0xF, 0xF, true));
        const float dt = d + dpart;
        const float p = __expf(dt * 0.35355339059327373f);
        lsum += p;
        ax = fmaf(p, kh.x, ax); ay = fmaf(p, kh.y, ay);
        az = fmaf(p, kh.z, az); aw = fmaf(p, kh.w, aw);
    }
    const float inv = 1.0f / lsum;
    const int b = bh >> 4, h = bh & 15;
    float4 o;
    o.x = ax * inv; o.y = ay * inv; o.z = az * inv; o.w = aw * inv;
    *(float4*)(ctx + (b * S_ + s0) * E_ + h * DK_ + half * 4) = o;
}

// ----------------------------------- ctx@Wo^T + bo + x -> LN1 -> x1, qout
// 4 rows/block, 1 row x 2 cols per thread, LN via 64-lane shuffle. grid 1024.
__global__ __launch_bounds__(256) void k_oproj_ln1(const float* __restrict__ ctx,
                                                   const float* __restrict__ WoT,
                                                   const float* __restrict__ bo,
                                                   const float* __restrict__ x,
                                                   const float* __restrict__ g1,
                                                   const float* __restrict__ bln1,
                                                   const float* __restrict__ ry,
                                                   float* __restrict__ x1,
                                                   float* __restrict__ qout) {
    __shared__ __attribute__((aligned(16))) float cs[4][128];
    const int tid = threadIdx.x;
    const int row0 = blockIdx.x * 4;
    if (tid < 128) ((float4*)cs)[tid] = ((const float4*)(ctx + row0 * E_))[tid];
    __syncthreads();
    const int r = tid >> 6, c0 = (tid & 63) * 2;
    const int gr = row0 + r;
    float a0 = 0.f, a1 = 0.f;
#pragma unroll 8
    for (int k = 0; k < 128; ++k) {
        const float2 w = *(const float2*)(WoT + k * 128 + c0);
        const float u = cs[r][k];
        a0 = fmaf(u, w.x, a0);
        a1 = fmaf(u, w.y, a1);
    }
    const float2 bb = *(const float2*)(bo + c0);
    const float2 xx = *(const float2*)(x + gr * E_ + c0);
    const float y0 = a0 + bb.x + xx.x;
    const float y1 = a1 + bb.y + xx.y;
    float s = y0 + y1;
    float q = fmaf(y0, y0, y1 * y1);
#pragma unroll
    for (int m = 1; m < 64; m <<= 1) {
        s += __shfl_xor(s, m);
        q += __shfl_xor(q, m);
    }
    const float mu = s * (1.0f / 128.0f);
    const float var = q * (1.0f / 128.0f) - mu * mu;
    const float is = rsqrtf(var + EPSV);
    const float2 gg = *(const float2*)(g1 + c0);
    const float2 lb = *(const float2*)(bln1 + c0);
    const float o0 = (y0 - mu) * is * gg.x + lb.x;
    const float o1 = (y1 - mu) * is * gg.y + lb.y;
    *(float2*)(x1 + gr * E_ + c0) = make_float2(o0, o1);
    if (c0 < 8) {
        const float qo0 = cosf(o0) * cosf(ry[c0]);
        const float qo1 = cosf(o1) * cosf(ry[c0 + 1]);
        *(float2*)(qout + gr * 8 + c0) = make_float2(qo0, qo1);
    }
}

// ------------------------- FFN (relu(qout@W1^T+b1)@W2^T+b2) + res + LN2
// 4 rows/block, grid 1024. h1 tile 4x512 in LDS (8 KB).
__global__ __launch_bounds__(256) void k_ffn_ln2(const float* __restrict__ qout,
                                                 const float* __restrict__ W1,
                                                 const float* __restrict__ b1,
                                                 const float* __restrict__ W2T,
                                                 const float* __restrict__ b2,
                                                 const float* __restrict__ x1,
                                                 const float* __restrict__ g2,
                                                 const float* __restrict__ bln2,
                                                 float* __restrict__ out) {
    __shared__ __attribute__((aligned(16))) float qs[4][8];
    __shared__ __attribute__((aligned(16))) float h1[4][512]; // 8 KB
    const int tid = threadIdx.x;
    const int row0 = blockIdx.x * 4;
    if (tid < 8) ((float4*)qs)[tid] = ((const float4*)(qout + row0 * 8))[tid];
    __syncthreads();
#pragma unroll
    for (int i = 0; i < 8; ++i) {
        const int idx = i * 256 + tid;
        const int rr = idx >> 9, f = idx & 511;   // rr uniform per i
        const float4 wa = *(const float4*)(W1 + f * 8);
        const float4 wb = *(const float4*)(W1 + f * 8 + 4);
        float v = b1[f];
        v = fmaf(qs[rr][0], wa.x, v); v = fmaf(qs[rr][1], wa.y, v);
        v = fmaf(qs[rr][2], wa.z, v); v = fmaf(qs[rr][3], wa.w, v);
        v = fmaf(qs[rr][4], wb.x, v); v = fmaf(qs[rr][5], wb.y, v);
        v = fmaf(qs[rr][6], wb.z, v); v = fmaf(qs[rr][7], wb.w, v);
        h1[rr][f] = fmaxf(v, 0.0f);
    }
    __syncthreads();
    const int r = tid >> 6, c0 = (tid & 63) * 2;
    const int gr = row0 + r;
    float a0 = 0.f, a1 = 0.f;
#pragma unroll 8
    for (int f = 0; f < F_; ++f) {
        const float2 w = *(const float2*)(W2T + f * 128 + c0);
        const float u = h1[r][f];
        a0 = fmaf(u, w.x, a0);
        a1 = fmaf(u, w.y, a1);
    }
    const float2 bb = *(const float2*)(b2 + c0);
    const float2 xx = *(const float2*)(x1 + gr * E_ + c0);
    const float y0 = a0 + bb.x + xx.x;
    const float y1 = a1 + bb.y + xx.y;
    float s = y0 + y1;
    float q = fmaf(y0, y0, y1 * y1);
#pragma unroll
    for (int m = 1; m < 64; m <<= 1) {
        s += __shfl_xor(s, m);
        q += __shfl_xor(q, m);
    }
    const float mu = s * (1.0f / 128.0f);
    const float var = q * (1.0f / 128.0f) - mu * mu;
    const float is = rsqrtf(var + EPSV);
    const float2 gg = *(const float2*)(g2 + c0);
    const float2 lb = *(const float2*)(bln2 + c0);
    const float o0 = (y0 - mu) * is * gg.x + lb.x;
    const float o1 = (y1 - mu) * is * gg.y + lb.y;
    *(float2*)(out + gr * E_ + c0) = make_float2(o0, o1);
}

extern "C" void kernel_launch(void* const* d_in, const int* in_sizes, int n_in,
                              void* d_out, int out_size, void* d_ws, size_t ws_size,
                              hipStream_t stream) {
    const float* x   = (const float*)d_in[0];
    const float* Wq  = (const float*)d_in[1];
    const float* bq  = (const float*)d_in[2];
    // d_in[3..6] = Wk, bk, Wv, bv : unused by the reference's output
    const float* rx  = (const float*)d_in[7];
    const float* Wo  = (const float*)d_in[8];
    const float* bo  = (const float*)d_in[9];
    const float* ry  = (const float*)d_in[10];
    const float* W1  = (const float*)d_in[11];
    const float* b1  = (const float*)d_in[12];
    const float* W2  = (const float*)d_in[13];
    const float* b2  = (const float*)d_in[14];
    const float* g1  = (const float*)d_in[15];
    const float* bl1 = (const float*)d_in[16];
    const float* g2  = (const float*)d_in[17];
    const float* bl2 = (const float*)d_in[18];
    float* ws  = (float*)d_ws;
    float* out = (float*)d_out;

    k_transpose<<<dim3(384), dim3(256), 0, stream>>>(Wq, Wo, W2, ws);
    k_qproj<<<dim3(R_ / 4), dim3(256), 0, stream>>>(x, bq, rx, ws + OFF_WQT, ws + OFF_QC);
    k_attn<<<dim3(B_ * H_ * 8), dim3(256), 0, stream>>>(ws + OFF_QC, ws + OFF_CTX);
    k_oproj_ln1<<<dim3(R_ / 4), dim3(256), 0, stream>>>(ws + OFF_CTX, ws + OFF_WOT, bo, x,
                                                        g1, bl1, ry,
                                                        ws + OFF_X1, ws + OFF_QOUT);
    k_ffn_ln2<<<dim3(R_ / 4), dim3(256), 0, stream>>>(ws + OFF_QOUT, W1, b1, ws + OFF_W2T,
                                                      b2, ws + OFF_X1, g2, bl2, out);
}

// Round 5
// 212.454 us; speedup vs baseline: 1.1950x; 1.1950x over previous
//
#include <hip/hip_runtime.h>
#include <math.h>

// Problem sizes (fixed by the reference)
constexpr int B_ = 4, S_ = 1024, E_ = 128, H_ = 16, DK_ = 8, F_ = 512;
constexpr int R_ = B_ * S_; // 4096 token rows
#define EPSV 1e-5f

// Workspace layout (float offsets). x1 reuses qc's region (qc dead after attn).
constexpr int OFF_WQT  = 0;
constexpr int OFF_WOT  = OFF_WQT + E_ * E_;   // 16384
constexpr int OFF_W2T  = OFF_WOT + E_ * E_;   // 32768
constexpr int OFF_QC   = OFF_W2T + F_ * E_;   // 98304
constexpr int OFF_X1   = OFF_QC;              // reuse (qc consumed by k_attn)
constexpr int OFF_CTX  = OFF_QC  + R_ * E_;   // 622592
constexpr int OFF_QOUT = OFF_CTX + R_ * E_;   // 1146880
// total ws need ≈ 4.7 MB

static __device__ __forceinline__ void fma4(float4& acc, float s, const float4 v) {
    acc.x = fmaf(s, v.x, acc.x);
    acc.y = fmaf(s, v.y, acc.y);
    acc.z = fmaf(s, v.z, acc.z);
    acc.w = fmaf(s, v.w, acc.w);
}

// ------------------------------------------------- transpose (reads coalesced)
__global__ __launch_bounds__(256) void k_transpose(const float* __restrict__ Wq,
                                                   const float* __restrict__ Wo,
                                                   const float* __restrict__ W2,
                                                   float* __restrict__ ws) {
    int idx = blockIdx.x * 256 + threadIdx.x;
    if (idx < 16384) {
        int e = idx >> 7, k = idx & 127;
        ws[OFF_WQT + k * 128 + e] = Wq[idx];
    } else if (idx < 32768) {
        int j = idx - 16384;
        int e = j >> 7, k = j & 127;
        ws[OFF_WOT + k * 128 + e] = Wo[j];
    } else if (idx < 98304) {
        int j = idx - 32768;
        int e = j >> 9, f = j & 511;           // W2 is [E=128][F=512]
        ws[OFF_W2T + f * 128 + e] = W2[j];
    }
}

// ------------------------------------------------- q projection + cos(+rx)
// 8 rows/block, 256 threads: thread = 1 row x 4 cols. grid 512.
__global__ __launch_bounds__(256) void k_qproj(const float* __restrict__ x,
                                               const float* __restrict__ bq,
                                               const float* __restrict__ rx,
                                               const float* __restrict__ WqT,
                                               float* __restrict__ qc) {
    __shared__ __attribute__((aligned(16))) float xs[8][128]; // 4 KB
    const int tid = threadIdx.x;
    const int row0 = blockIdx.x * 8;
    ((float4*)xs)[tid] = ((const float4*)(x + row0 * E_))[tid];
    __syncthreads();
    const int cg = tid & 31, rs = tid >> 5;
    const int c0 = cg * 4;
    const float* wp = WqT + c0;
    float4 acc = {0.f, 0.f, 0.f, 0.f};
#pragma unroll 4
    for (int k0 = 0; k0 < 128; k0 += 4) {
        const float4 u  = *(const float4*)&xs[rs][k0];
        const float4 w0 = *(const float4*)(wp + (k0 + 0) * 128);
        const float4 w1 = *(const float4*)(wp + (k0 + 1) * 128);
        const float4 w2 = *(const float4*)(wp + (k0 + 2) * 128);
        const float4 w3 = *(const float4*)(wp + (k0 + 3) * 128);
        fma4(acc, u.x, w0);
        fma4(acc, u.y, w1);
        fma4(acc, u.z, w2);
        fma4(acc, u.w, w3);
    }
    const float4 bb = *(const float4*)(bq + c0);
    const float4 rr = *(const float4*)(rx + c0);
    const int gr = row0 + rs;
    const int b = gr >> 10, s = gr & 1023;
    const int h = c0 >> 3, d0 = c0 & 7;
    float4 o;
    o.x = cosf(acc.x + bb.x + rr.x);
    o.y = cosf(acc.y + bb.y + rr.y);
    o.z = cosf(acc.z + bb.z + rr.z);
    o.w = cosf(acc.w + bb.w + rr.w);
    *(float4*)(qc + (((b * H_ + h) * S_ + s) * DK_ + d0)) = o;
}

// ---------------------------------------------------------------- attention
// Bounded scores -> softmax without max subtraction. 2 lanes per query (each
// owns 4 of 8 dims); full dot via DPP quad-swap. K read straight from global
// (uniform per lane-pair -> one cache line per key). grid = 64 (b,h) * 8.
__global__ __launch_bounds__(256) void k_attn(const float* __restrict__ qc,
                                              float* __restrict__ ctx) {
    const int tid = threadIdx.x;
    const int bh = blockIdx.x >> 3;
    const int qt = blockIdx.x & 7;
    const float* kbase = qc + bh * (S_ * DK_);
    const int ql = tid >> 1, half = tid & 1;
    const int s0 = qt * 128 + ql;
    const float4 qh = *(const float4*)(kbase + s0 * 8 + half * 4);
    float ax = 0.f, ay = 0.f, az = 0.f, aw = 0.f, lsum = 0.f;
#pragma unroll 8
    for (int t = 0; t < S_; ++t) {
        const float4 kh = *(const float4*)(kbase + t * 8 + half * 4);
        float d = qh.x * kh.x;
        d = fmaf(qh.y, kh.y, d);
        d = fmaf(qh.z, kh.z, d);
        d = fmaf(qh.w, kh.w, d);
        // partner lane's partial dot: quad_perm [1,0,3,2] = 0xB1
        const float dpart = __int_as_float(
            __builtin_amdgcn_mov_dpp(__float_as_int(d), 0xB1, 0xF, 0xF, true));
        const float dt = d + dpart;
        const float p = __expf(dt * 0.35355339059327373f);
        lsum += p;
        ax = fmaf(p, kh.x, ax); ay = fmaf(p, kh.y, ay);
        az = fmaf(p, kh.z, az); aw = fmaf(p, kh.w, aw);
    }
    const float inv = 1.0f / lsum;
    const int b = bh >> 4, h = bh & 15;
    float4 o;
    o.x = ax * inv; o.y = ay * inv; o.z = az * inv; o.w = aw * inv;
    *(float4*)(ctx + (b * S_ + s0) * E_ + h * DK_ + half * 4) = o;
}

// ----------------------------------- ctx@Wo^T + bo + x -> LN1 -> x1, qout
// 8 rows/block, thread = 1 row x 4 cols, LN via half-wave shuffle. grid 512.
__global__ __launch_bounds__(256) void k_oproj_ln1(const float* __restrict__ ctx,
                                                   const float* __restrict__ WoT,
                                                   const float* __restrict__ bo,
                                                   const float* __restrict__ x,
                                                   const float* __restrict__ g1,
                                                   const float* __restrict__ bln1,
                                                   const float* __restrict__ ry,
                                                   float* __restrict__ x1,
                                                   float* __restrict__ qout) {
    __shared__ __attribute__((aligned(16))) float cs[8][128]; // 4 KB
    const int tid = threadIdx.x;
    const int row0 = blockIdx.x * 8;
    ((float4*)cs)[tid] = ((const float4*)(ctx + row0 * E_))[tid];
    __syncthreads();
    const int cg = tid & 31, rs = tid >> 5;
    const int c0 = cg * 4;
    const float* wp = WoT + c0;
    float4 acc = {0.f, 0.f, 0.f, 0.f};
#pragma unroll 4
    for (int k0 = 0; k0 < 128; k0 += 4) {
        const float4 u  = *(const float4*)&cs[rs][k0];
        const float4 w0 = *(const float4*)(wp + (k0 + 0) * 128);
        const float4 w1 = *(const float4*)(wp + (k0 + 1) * 128);
        const float4 w2 = *(const float4*)(wp + (k0 + 2) * 128);
        const float4 w3 = *(const float4*)(wp + (k0 + 3) * 128);
        fma4(acc, u.x, w0);
        fma4(acc, u.y, w1);
        fma4(acc, u.z, w2);
        fma4(acc, u.w, w3);
    }
    const int gr = row0 + rs;
    const float4 bb = *(const float4*)(bo + c0);
    const float4 xx = *(const float4*)(x + gr * E_ + c0);
    float4 y;
    y.x = acc.x + bb.x + xx.x;
    y.y = acc.y + bb.y + xx.y;
    y.z = acc.z + bb.z + xx.z;
    y.w = acc.w + bb.w + xx.w;
    float s = (y.x + y.y) + (y.z + y.w);
    float q = fmaf(y.x, y.x, y.y * y.y) + fmaf(y.z, y.z, y.w * y.w);
#pragma unroll
    for (int m = 1; m < 32; m <<= 1) {  // reduce across the 32-lane row group
        s += __shfl_xor(s, m);
        q += __shfl_xor(q, m);
    }
    const float mu = s * (1.0f / 128.0f);
    const float var = q * (1.0f / 128.0f) - mu * mu;
    const float is = rsqrtf(var + EPSV);
    const float4 gg = *(const float4*)(g1 + c0);
    const float4 lb = *(const float4*)(bln1 + c0);
    float4 o;
    o.x = (y.x - mu) * is * gg.x + lb.x;
    o.y = (y.y - mu) * is * gg.y + lb.y;
    o.z = (y.z - mu) * is * gg.z + lb.z;
    o.w = (y.w - mu) * is * gg.w + lb.w;
    *(float4*)(x1 + gr * E_ + c0) = o;
    if (c0 < 8) {
        float4 qo;
        qo.x = cosf(o.x) * cosf(ry[c0 + 0]);
        qo.y = cosf(o.y) * cosf(ry[c0 + 1]);
        qo.z = cosf(o.z) * cosf(ry[c0 + 2]);
        qo.w = cosf(o.w) * cosf(ry[c0 + 3]);
        *(float4*)(qout + gr * 8 + c0) = qo;
    }
}

// ------------------------- FFN (relu(qout@W1^T+b1)@W2^T+b2) + res + LN2
// 8 rows/block, grid 512. h1 tile 8x512 in LDS (16 KB).
__global__ __launch_bounds__(256) void k_ffn_ln2(const float* __restrict__ qout,
                                                 const float* __restrict__ W1,
                                                 const float* __restrict__ b1,
                                                 const float* __restrict__ W2T,
                                                 const float* __restrict__ b2,
                                                 const float* __restrict__ x1,
                                                 const float* __restrict__ g2,
                                                 const float* __restrict__ bln2,
                                                 float* __restrict__ out) {
    __shared__ __attribute__((aligned(16))) float qs[8][8];
    __shared__ __attribute__((aligned(16))) float h1[8][512]; // 16 KB
    const int tid = threadIdx.x;
    const int row0 = blockIdx.x * 8;
    if (tid < 16) ((float4*)qs)[tid] = ((const float4*)(qout + row0 * 8))[tid];
    __syncthreads();
#pragma unroll
    for (int i = 0; i < 16; ++i) {
        const int f = ((i & 1) << 8) + tid;
        const int r = i >> 1;                     // uniform per iteration
        const float4 wa = *(const float4*)(W1 + f * 8);
        const float4 wb = *(const float4*)(W1 + f * 8 + 4);
        float v = b1[f];
        v = fmaf(qs[r][0], wa.x, v); v = fmaf(qs[r][1], wa.y, v);
        v = fmaf(qs[r][2], wa.z, v); v = fmaf(qs[r][3], wa.w, v);
        v = fmaf(qs[r][4], wb.x, v); v = fmaf(qs[r][5], wb.y, v);
        v = fmaf(qs[r][6], wb.z, v); v = fmaf(qs[r][7], wb.w, v);
        h1[r][f] = fmaxf(v, 0.0f);
    }
    __syncthreads();
    const int cg = tid & 31, rs = tid >> 5;
    const int c0 = cg * 4;
    const float* wp = W2T + c0;
    float4 acc = {0.f, 0.f, 0.f, 0.f};
#pragma unroll 4
    for (int f0 = 0; f0 < 512; f0 += 4) {
        const float4 u  = *(const float4*)&h1[rs][f0];
        const float4 w0 = *(const float4*)(wp + (f0 + 0) * 128);
        const float4 w1 = *(const float4*)(wp + (f0 + 1) * 128);
        const float4 w2 = *(const float4*)(wp + (f0 + 2) * 128);
        const float4 w3 = *(const float4*)(wp + (f0 + 3) * 128);
        fma4(acc, u.x, w0);
        fma4(acc, u.y, w1);
        fma4(acc, u.z, w2);
        fma4(acc, u.w, w3);
    }
    const int gr = row0 + rs;
    const float4 bb = *(const float4*)(b2 + c0);
    const float4 xx = *(const float4*)(x1 + gr * E_ + c0);
    float4 y;
    y.x = acc.x + bb.x + xx.x;
    y.y = acc.y + bb.y + xx.y;
    y.z = acc.z + bb.z + xx.z;
    y.w = acc.w + bb.w + xx.w;
    float s = (y.x + y.y) + (y.z + y.w);
    float q = fmaf(y.x, y.x, y.y * y.y) + fmaf(y.z, y.z, y.w * y.w);
#pragma unroll
    for (int m = 1; m < 32; m <<= 1) {
        s += __shfl_xor(s, m);
        q += __shfl_xor(q, m);
    }
    const float mu = s * (1.0f / 128.0f);
    const float var = q * (1.0f / 128.0f) - mu * mu;
    const float is = rsqrtf(var + EPSV);
    const float4 gg = *(const float4*)(g2 + c0);
    const float4 lb = *(const float4*)(bln2 + c0);
    float4 o;
    o.x = (y.x - mu) * is * gg.x + lb.x;
    o.y = (y.y - mu) * is * gg.y + lb.y;
    o.z = (y.z - mu) * is * gg.z + lb.z;
    o.w = (y.w - mu) * is * gg.w + lb.w;
    *(float4*)(out + gr * E_ + c0) = o;
}

extern "C" void kernel_launch(void* const* d_in, const int* in_sizes, int n_in,
                              void* d_out, int out_size, void* d_ws, size_t ws_size,
                              hipStream_t stream) {
    const float* x   = (const float*)d_in[0];
    const float* Wq  = (const float*)d_in[1];
    const float* bq  = (const float*)d_in[2];
    // d_in[3..6] = Wk, bk, Wv, bv : unused by the reference's output
    const float* rx  = (const float*)d_in[7];
    const float* Wo  = (const float*)d_in[8];
    const float* bo  = (const float*)d_in[9];
    const float* ry  = (const float*)d_in[10];
    const float* W1  = (const float*)d_in[11];
    const float* b1  = (const float*)d_in[12];
    const float* W2  = (const float*)d_in[13];
    const float* b2  = (const float*)d_in[14];
    const float* g1  = (const float*)d_in[15];
    const float* bl1 = (const float*)d_in[16];
    const float* g2  = (const float*)d_in[17];
    const float* bl2 = (const float*)d_in[18];
    float* ws  = (float*)d_ws;
    float* out = (float*)d_out;

    k_transpose<<<dim3(384), dim3(256), 0, stream>>>(Wq, Wo, W2, ws);
    k_qproj<<<dim3(R_ / 8), dim3(256), 0, stream>>>(x, bq, rx, ws + OFF_WQT, ws + OFF_QC);
    k_attn<<<dim3(B_ * H_ * 8), dim3(256), 0, stream>>>(ws + OFF_QC, ws + OFF_CTX);
    k_oproj_ln1<<<dim3(R_ / 8), dim3(256), 0, stream>>>(ws + OFF_CTX, ws + OFF_WOT, bo, x,
                                                        g1, bl1, ry,
                                                        ws + OFF_X1, ws + OFF_QOUT);
    k_ffn_ln2<<<dim3(R_ / 8), dim3(256), 0, stream>>>(ws + OFF_QOUT, W1, b1, ws + OFF_W2T,
                                                      b2, ws + OFF_X1, g2, bl2, out);
}

// Round 8
// 181.175 us; speedup vs baseline: 1.4013x; 1.1726x over previous
//
#include <hip/hip_runtime.h>
#include <math.h>

// Problem sizes (fixed by the reference)
constexpr int B_ = 4, S_ = 1024, E_ = 128, H_ = 16, DK_ = 8, F_ = 512;
constexpr int R_ = B_ * S_; // 4096 token rows
#define EPSV 1e-5f

// Workspace layout (float offsets).
constexpr int OFF_WQT  = 0;
constexpr int OFF_WOT  = OFF_WQT + E_ * E_;     // 16384
constexpr int OFF_W2T  = OFF_WOT + E_ * E_;     // 32768
constexpr int OFF_QCB  = OFF_W2T + F_ * E_;     // 98304   (bf16 Q/K [64][1024][8], 1 MB)
constexpr int OFF_VTB  = OFF_QCB + 262144;      // 360448  (bf16 V^T [64][8][1024], 1 MB)
constexpr int OFF_X1   = OFF_QCB;               // reuse (qcb/vtb dead after attn)
constexpr int OFF_CTX  = OFF_VTB + 262144;      // 622592
constexpr int OFF_QOUT = OFF_CTX + R_ * E_;     // 1146880
// total ws ≈ 4.7 MB

typedef __attribute__((ext_vector_type(4)))  short short4v;
typedef __attribute__((ext_vector_type(16))) float f32x16;

static __device__ __forceinline__ void fma4(float4& acc, float s, const float4 v) {
    acc.x = fmaf(s, v.x, acc.x);
    acc.y = fmaf(s, v.y, acc.y);
    acc.z = fmaf(s, v.z, acc.z);
    acc.w = fmaf(s, v.w, acc.w);
}

static __device__ __forceinline__ short4v pack2(unsigned a, unsigned b) {
    union { unsigned u[2]; short4v s; } t;
    t.u[0] = a; t.u[1] = b;
    return t.s;
}

// 4× f32 -> 4× bf16 (RNE) via hardware cvt_pk
static __device__ __forceinline__ short4v cvt4_bf16(float a, float b, float c, float d) {
    unsigned p0, p1;
    asm("v_cvt_pk_bf16_f32 %0, %1, %2" : "=v"(p0) : "v"(a), "v"(b));
    asm("v_cvt_pk_bf16_f32 %0, %1, %2" : "=v"(p1) : "v"(c), "v"(d));
    return pack2(p0, p1);
}

// ------------------------------------------------- transpose (reads coalesced)
__global__ __launch_bounds__(256) void k_transpose(const float* __restrict__ Wq,
                                                   const float* __restrict__ Wo,
                                                   const float* __restrict__ W2,
                                                   float* __restrict__ ws) {
    int idx = blockIdx.x * 256 + threadIdx.x;
    if (idx < 16384) {
        int e = idx >> 7, k = idx & 127;
        ws[OFF_WQT + k * 128 + e] = Wq[idx];
    } else if (idx < 32768) {
        int j = idx - 16384;
        int e = j >> 7, k = j & 127;
        ws[OFF_WOT + k * 128 + e] = Wo[j];
    } else if (idx < 98304) {
        int j = idx - 32768;
        int e = j >> 9, f = j & 511;           // W2 is [E=128][F=512]
        ws[OFF_W2T + f * 128 + e] = W2[j];
    }
}

// ------------------------------------------------- q projection + cos(+rx)
// 8 rows/block, 256 threads: thread = 1 row x 4 cols. grid 512.
// Emits bf16 qcb[bh][s][8] and bf16 vtb[bh][8][s] (V == K == cos(q+rx)).
__global__ __launch_bounds__(256) void k_qproj(const float* __restrict__ x,
                                               const float* __restrict__ bq,
                                               const float* __restrict__ rx,
                                               const float* __restrict__ WqT,
                                               short* __restrict__ qcb,
                                               short* __restrict__ vtb) {
    __shared__ __attribute__((aligned(16))) float xs[8][128]; // 4 KB
    const int tid = threadIdx.x;
    const int row0 = blockIdx.x * 8;
    ((float4*)xs)[tid] = ((const float4*)(x + row0 * E_))[tid];
    __syncthreads();
    const int cg = tid & 31, rs = tid >> 5;
    const int c0 = cg * 4;
    const float* wp = WqT + c0;
    float4 acc = {0.f, 0.f, 0.f, 0.f};
#pragma unroll 4
    for (int k0 = 0; k0 < 128; k0 += 4) {
        const float4 u  = *(const float4*)&xs[rs][k0];
        const float4 w0 = *(const float4*)(wp + (k0 + 0) * 128);
        const float4 w1 = *(const float4*)(wp + (k0 + 1) * 128);
        const float4 w2 = *(const float4*)(wp + (k0 + 2) * 128);
        const float4 w3 = *(const float4*)(wp + (k0 + 3) * 128);
        fma4(acc, u.x, w0);
        fma4(acc, u.y, w1);
        fma4(acc, u.z, w2);
        fma4(acc, u.w, w3);
    }
    const float4 bb = *(const float4*)(bq + c0);
    const float4 rr = *(const float4*)(rx + c0);
    const int gr = row0 + rs;
    const int b = gr >> 10, s = gr & 1023;
    const int h = c0 >> 3, d0 = c0 & 7;
    const int bh = b * H_ + h;
    float4 o;
    o.x = cosf(acc.x + bb.x + rr.x);
    o.y = cosf(acc.y + bb.y + rr.y);
    o.z = cosf(acc.z + bb.z + rr.z);
    o.w = cosf(acc.w + bb.w + rr.w);
    const short4v q4 = cvt4_bf16(o.x, o.y, o.z, o.w);
    *(short4v*)(qcb + (size_t)(bh * S_ + s) * 8 + d0) = q4;
    vtb[(bh * 8 + d0 + 0) * S_ + s] = q4[0];
    vtb[(bh * 8 + d0 + 1) * S_ + s] = q4[1];
    vtb[(bh * 8 + d0 + 2) * S_ + s] = q4[2];
    vtb[(bh * 8 + d0 + 3) * S_ + s] = q4[3];
}

// ---------------------------------------------------------------- attention
// MFMA flash-style, no max subtraction (|scores| <= 2.83).
// Per wave: 32 queries x 1024 keys. S^T = K·Q^T via mfma_32x32x8_bf16;
// D(P^T) regs 4c..4c+3 feed the PV mfma B-frag for t-chunk tc=8c directly.
// grid = 64 bh * 8 blocks of 4 waves (128 q / block).
__global__ __launch_bounds__(256) void k_attn(const short* __restrict__ qcb,
                                              const short* __restrict__ vtb,
                                              float* __restrict__ ctx) {
    constexpr float SC = 0.35355339059327373f;
    const int tid = threadIdx.x;
    const int bh = blockIdx.x >> 3;
    const int qt = blockIdx.x & 7;
    const int lane = tid & 63;
    const int row = lane & 31, hi = lane >> 5;
    const int q0 = qt * 128 + (tid >> 6) * 32;

    // B-frag: Q rows (fixed per wave): Q[q0+row][4*hi + j]
    const short4v qfrag = *(const short4v*)(qcb + (size_t)(bh * S_ + q0 + row) * 8 + 4 * hi);
    // A-frag source for scores: K rows
    const short* kb = qcb + (size_t)bh * S_ * 8 + 4 * hi;
    // A-frag source for PV: V^T rows (only d = row < 8 are real; others zeroed)
    const bool vok = row < 8;
    const short* vb = vtb + (size_t)(bh * 8 + (row & 7)) * S_ + 4 * hi;
    const short4v zf = {0, 0, 0, 0};

    f32x16 pacc = {0,0,0,0,0,0,0,0,0,0,0,0,0,0,0,0};
    const f32x16 zacc = {0,0,0,0,0,0,0,0,0,0,0,0,0,0,0,0};
    float lsum = 0.f;

#pragma unroll 2
    for (int tk = 0; tk < S_; tk += 32) {
        const short4v kfrag = *(const short4v*)(kb + (size_t)(tk + row) * 8);
        // S^T tile: D[t,q], col=q=lane&31, row=t=(reg&3)+8*(reg>>2)+4*hi
        f32x16 sd = __builtin_amdgcn_mfma_f32_32x32x8bf16_1k(kfrag, qfrag, zacc, 0, 0, 0);

        short4v pb0, pb1, pb2, pb3;
#define PCHUNK(c, pbv) { \
        const float e0 = __expf(sd[4*(c)+0] * SC); \
        const float e1 = __expf(sd[4*(c)+1] * SC); \
        const float e2 = __expf(sd[4*(c)+2] * SC); \
        const float e3 = __expf(sd[4*(c)+3] * SC); \
        lsum += (e0 + e1) + (e2 + e3); \
        pbv = cvt4_bf16(e0, e1, e2, e3); }
        PCHUNK(0, pb0)
        PCHUNK(1, pb1)
        PCHUNK(2, pb2)
        PCHUNK(3, pb3)
#undef PCHUNK

        const short4v v0 = vok ? *(const short4v*)(vb + tk +  0) : zf;
        const short4v v1 = vok ? *(const short4v*)(vb + tk +  8) : zf;
        const short4v v2 = vok ? *(const short4v*)(vb + tk + 16) : zf;
        const short4v v3 = vok ? *(const short4v*)(vb + tk + 24) : zf;
        // ctx^T[d,q] += V^T[d, tc..] · P^T[tc.., q]
        pacc = __builtin_amdgcn_mfma_f32_32x32x8bf16_1k(v0, pb0, pacc, 0, 0, 0);
        pacc = __builtin_amdgcn_mfma_f32_32x32x8bf16_1k(v1, pb1, pacc, 0, 0, 0);
        pacc = __builtin_amdgcn_mfma_f32_32x32x8bf16_1k(v2, pb2, pacc, 0, 0, 0);
        pacc = __builtin_amdgcn_mfma_f32_32x32x8bf16_1k(v3, pb3, pacc, 0, 0, 0);
    }

    // lane holds half the t-range for its q; partner lane (^32) has the rest
    lsum += __shfl_xor(lsum, 32);
    const float inv = 1.0f / lsum;
    // pacc regs 0..3 hold d = 4*hi + {0,1,2,3} for q = q0+row
    const int b = bh >> 4, h = bh & 15;
    float4 o;
    o.x = pacc[0] * inv; o.y = pacc[1] * inv;
    o.z = pacc[2] * inv; o.w = pacc[3] * inv;
    *(float4*)(ctx + (size_t)(b * S_ + q0 + row) * E_ + h * 8 + 4 * hi) = o;
}

// ----------------------------------- ctx@Wo^T + bo + x -> LN1 -> x1, qout
// 8 rows/block, thread = 1 row x 4 cols, LN via half-wave shuffle. grid 512.
__global__ __launch_bounds__(256) void k_oproj_ln1(const float* __restrict__ ctx,
                                                   const float* __restrict__ WoT,
                                                   const float* __restrict__ bo,
                                                   const float* __restrict__ x,
                                                   const float* __restrict__ g1,
                                                   const float* __restrict__ bln1,
                                                   const float* __restrict__ ry,
                                                   float* __restrict__ x1,
                                                   float* __restrict__ qout) {
    __shared__ __attribute__((aligned(16))) float cs[8][128]; // 4 KB
    const int tid = threadIdx.x;
    const int row0 = blockIdx.x * 8;
    ((float4*)cs)[tid] = ((const float4*)(ctx + row0 * E_))[tid];
    __syncthreads();
    const int cg = tid & 31, rs = tid >> 5;
    const int c0 = cg * 4;
    const float* wp = WoT + c0;
    float4 acc = {0.f, 0.f, 0.f, 0.f};
#pragma unroll 4
    for (int k0 = 0; k0 < 128; k0 += 4) {
        const float4 u  = *(const float4*)&cs[rs][k0];
        const float4 w0 = *(const float4*)(wp + (k0 + 0) * 128);
        const float4 w1 = *(const float4*)(wp + (k0 + 1) * 128);
        const float4 w2 = *(const float4*)(wp + (k0 + 2) * 128);
        const float4 w3 = *(const float4*)(wp + (k0 + 3) * 128);
        fma4(acc, u.x, w0);
        fma4(acc, u.y, w1);
        fma4(acc, u.z, w2);
        fma4(acc, u.w, w3);
    }
    const int gr = row0 + rs;
    const float4 bb = *(const float4*)(bo + c0);
    const float4 xx = *(const float4*)(x + gr * E_ + c0);
    float4 y;
    y.x = acc.x + bb.x + xx.x;
    y.y = acc.y + bb.y + xx.y;
    y.z = acc.z + bb.z + xx.z;
    y.w = acc.w + bb.w + xx.w;
    float s = (y.x + y.y) + (y.z + y.w);
    float q = fmaf(y.x, y.x, y.y * y.y) + fmaf(y.z, y.z, y.w * y.w);
#pragma unroll
    for (int m = 1; m < 32; m <<= 1) {  // reduce across the 32-lane row group
        s += __shfl_xor(s, m);
        q += __shfl_xor(q, m);
    }
    const float mu = s * (1.0f / 128.0f);
    const float var = q * (1.0f / 128.0f) - mu * mu;
    const float is = rsqrtf(var + EPSV);
    const float4 gg = *(const float4*)(g1 + c0);
    const float4 lb = *(const float4*)(bln1 + c0);
    float4 o;
    o.x = (y.x - mu) * is * gg.x + lb.x;
    o.y = (y.y - mu) * is * gg.y + lb.y;
    o.z = (y.z - mu) * is * gg.z + lb.z;
    o.w = (y.w - mu) * is * gg.w + lb.w;
    *(float4*)(x1 + gr * E_ + c0) = o;
    if (c0 < 8) {
        float4 qo;
        qo.x = cosf(o.x) * cosf(ry[c0 + 0]);
        qo.y = cosf(o.y) * cosf(ry[c0 + 1]);
        qo.z = cosf(o.z) * cosf(ry[c0 + 2]);
        qo.w = cosf(o.w) * cosf(ry[c0 + 3]);
        *(float4*)(qout + gr * 8 + c0) = qo;
    }
}

// ------------------------- FFN (relu(qout@W1^T+b1)@W2^T+b2) + res + LN2
// 8 rows/block, grid 512. h1 tile 8x512 in LDS (16 KB).
__global__ __launch_bounds__(256) void k_ffn_ln2(const float* __restrict__ qout,
                                                 const float* __restrict__ W1,
                                                 const float* __restrict__ b1,
                                                 const float* __restrict__ W2T,
                                                 const float* __restrict__ b2,
                                                 const float* __restrict__ x1,
                                                 const float* __restrict__ g2,
                                                 const float* __restrict__ bln2,
                                                 float* __restrict__ out) {
    __shared__ __attribute__((aligned(16))) float qs[8][8];
    __shared__ __attribute__((aligned(16))) float h1[8][512]; // 16 KB
    const int tid = threadIdx.x;
    const int row0 = blockIdx.x * 8;
    if (tid < 16) ((float4*)qs)[tid] = ((const float4*)(qout + row0 * 8))[tid];
    __syncthreads();
#pragma unroll
    for (int i = 0; i < 16; ++i) {
        const int f = ((i & 1) << 8) + tid;
        const int r = i >> 1;                     // uniform per iteration
        const float4 wa = *(const float4*)(W1 + f * 8);
        const float4 wb = *(const float4*)(W1 + f * 8 + 4);
        float v = b1[f];
        v = fmaf(qs[r][0], wa.x, v); v = fmaf(qs[r][1], wa.y, v);
        v = fmaf(qs[r][2], wa.z, v); v = fmaf(qs[r][3], wa.w, v);
        v = fmaf(qs[r][4], wb.x, v); v = fmaf(qs[r][5], wb.y, v);
        v = fmaf(qs[r][6], wb.z, v); v = fmaf(qs[r][7], wb.w, v);
        h1[r][f] = fmaxf(v, 0.0f);
    }
    __syncthreads();
    const int cg = tid & 31, rs = tid >> 5;
    const int c0 = cg * 4;
    const float* wp = W2T + c0;
    float4 acc = {0.f, 0.f, 0.f, 0.f};
#pragma unroll 4
    for (int f0 = 0; f0 < 512; f0 += 4) {
        const float4 u  = *(const float4*)&h1[rs][f0];
        const float4 w0 = *(const float4*)(wp + (f0 + 0) * 128);
        const float4 w1 = *(const float4*)(wp + (f0 + 1) * 128);
        const float4 w2 = *(const float4*)(wp + (f0 + 2) * 128);
        const float4 w3 = *(const float4*)(wp + (f0 + 3) * 128);
        fma4(acc, u.x, w0);
        fma4(acc, u.y, w1);
        fma4(acc, u.z, w2);
        fma4(acc, u.w, w3);
    }
    const int gr = row0 + rs;
    const float4 bb = *(const float4*)(b2 + c0);
    const float4 xx = *(const float4*)(x1 + gr * E_ + c0);
    float4 y;
    y.x = acc.x + bb.x + xx.x;
    y.y = acc.y + bb.y + xx.y;
    y.z = acc.z + bb.z + xx.z;
    y.w = acc.w + bb.w + xx.w;
    float s = (y.x + y.y) + (y.z + y.w);
    float q = fmaf(y.x, y.x, y.y * y.y) + fmaf(y.z, y.z, y.w * y.w);
#pragma unroll
    for (int m = 1; m < 32; m <<= 1) {
        s += __shfl_xor(s, m);
        q += __shfl_xor(q, m);
    }
    const float mu = s * (1.0f / 128.0f);
    const float var = q * (1.0f / 128.0f) - mu * mu;
    const float is = rsqrtf(var + EPSV);
    const float4 gg = *(const float4*)(g2 + c0);
    const float4 lb = *(const float4*)(bln2 + c0);
    float4 o;
    o.x = (y.x - mu) * is * gg.x + lb.x;
    o.y = (y.y - mu) * is * gg.y + lb.y;
    o.z = (y.z - mu) * is * gg.z + lb.z;
    o.w = (y.w - mu) * is * gg.w + lb.w;
    *(float4*)(out + gr * E_ + c0) = o;
}

extern "C" void kernel_launch(void* const* d_in, const int* in_sizes, int n_in,
                              void* d_out, int out_size, void* d_ws, size_t ws_size,
                              hipStream_t stream) {
    const float* x   = (const float*)d_in[0];
    const float* Wq  = (const float*)d_in[1];
    const float* bq  = (const float*)d_in[2];
    // d_in[3..6] = Wk, bk, Wv, bv : unused by the reference's output
    const float* rx  = (const float*)d_in[7];
    const float* Wo  = (const float*)d_in[8];
    const float* bo  = (const float*)d_in[9];
    const float* ry  = (const float*)d_in[10];
    const float* W1  = (const float*)d_in[11];
    const float* b1  = (const float*)d_in[12];
    const float* W2  = (const float*)d_in[13];
    const float* b2  = (const float*)d_in[14];
    const float* g1  = (const float*)d_in[15];
    const float* bl1 = (const float*)d_in[16];
    const float* g2  = (const float*)d_in[17];
    const float* bl2 = (const float*)d_in[18];
    float* ws  = (float*)d_ws;
    float* out = (float*)d_out;
    short* qcb = (short*)(ws + OFF_QCB);
    short* vtb = (short*)(ws + OFF_VTB);

    k_transpose<<<dim3(384), dim3(256), 0, stream>>>(Wq, Wo, W2, ws);
    k_qproj<<<dim3(R_ / 8), dim3(256), 0, stream>>>(x, bq, rx, ws + OFF_WQT, qcb, vtb);
    k_attn<<<dim3(B_ * H_ * 8), dim3(256), 0, stream>>>(qcb, vtb, ws + OFF_CTX);
    k_oproj_ln1<<<dim3(R_ / 8), dim3(256), 0, stream>>>(ws + OFF_CTX, ws + OFF_WOT, bo, x,
                                                        g1, bl1, ry,
                                                        ws + OFF_X1, ws + OFF_QOUT);
    k_ffn_ln2<<<dim3(R_ / 8), dim3(256), 0, stream>>>(ws + OFF_QOUT, W1, b1, ws + OFF_W2T,
                                                      b2, ws + OFF_X1, g2, bl2, out);
}